// Round 12
// baseline (357.523 us; speedup 1.0000x reference)
//
#include <hip/hip_runtime.h>

#define PI_F 3.14159265358979323846f

typedef _Float16 h8 __attribute__((ext_vector_type(8)));
typedef _Float16 h2v __attribute__((ext_vector_type(2)));
typedef float f4 __attribute__((ext_vector_type(4)));
typedef unsigned int u32;

struct Geom { float enc[8]; float h0, h1, h2; };

__device__ __forceinline__ bool geom_of(const float* __restrict__ r, int e, Geom& g) {
  const float rx = r[3*e], ry = r[3*e+1], rz = r[3*e+2];
  const float xsq = (rx*rx + ry*ry + rz*rz) * (1.0f/2.5f);
  const float cut = 1.0f - xsq;
  if (cut <= 0.0f) return false;
  const float c1 = cosf(PI_F * sqrtf(xsq));
  g.enc[0] = cut; g.enc[1] = c1*cut;
  float cp = 1.0f, cc = c1;
  #pragma unroll
  for (int n = 2; n < 8; n++) { float cn = 2.0f*c1*cc - cp; cp = cc; cc = cn; g.enc[n] = cn*cut; }
  const float s = 7.0f/2.5f;
  const float yx = rx*s, yy = ry*s, yz = rz*s;
  const float inv = rsqrtf(1.0f + yx*yx + yy*yy + yz*yz);
  g.h0 = yx*inv; g.h1 = yy*inv; g.h2 = yz*inv;
  return true;
}

// branchless: dead slot (r=0) or cut<=0 -> enc=0 -> zero contribution
__device__ __forceinline__ void geom_full(float rx, float ry, float rz, Geom& g) {
  const float xsq = (rx*rx + ry*ry + rz*rz) * (1.0f/2.5f);
  const float cut = fmaxf(1.0f - xsq, 0.0f);
  const float c1 = cosf(PI_F * sqrtf(xsq));
  g.enc[0] = cut; g.enc[1] = c1*cut;
  float cp = 1.0f, cc = c1;
  #pragma unroll
  for (int n = 2; n < 8; n++) { float cn = 2.0f*c1*cc - cp; cp = cc; cc = cn; g.enc[n] = cn*cut; }
  const float s = 7.0f/2.5f;
  const float yx = rx*s, yy = ry*s, yz = rz*s;
  const float inv = rsqrtf(1.0f + yx*yx + yy*yy + yz*yz);
  g.h0 = yx*inv; g.h1 = yy*inv; g.h2 = yz*inv;
}

__device__ __forceinline__ u32 pk2(float a, float b) {
  union { h2v h; u32 u; } r;
  r.h.x = (_Float16)a; r.h.y = (_Float16)b;
  return r.u;
}

__device__ __forceinline__ h8 mul_enc(uint4 c, u32 e) {
  union { uint4 u; h2v p[4]; } C; C.u = c;
  union { u32 u; h2v h; } E; E.u = e;
  union { h2v p[4]; h8 v; } R;
  #pragma unroll
  for (int i = 0; i < 4; i++) R.p[i] = C.p[i] * E.h;
  return R.v;
}

__device__ __forceinline__ h8 as_h8(uint4 c) { union { uint4 u; h8 v; } r; r.u = c; return r.v; }

__device__ __forceinline__ void wave_lds_fence() {
  asm volatile("s_waitcnt lgkmcnt(0)" ::: "memory");
  __builtin_amdgcn_sched_barrier(0);
}

// full per-lane edge slice (S and V ranks): all named fields, no arrays
struct GBuf {
  float4 a0, a1, v0, v1, v2;
  float2 d0, d1, d2, d3, d4, d5, d6, d7, d8;
  float rx, ry, rz;
};
// lite slice (D rank): xd loaded at pack time
struct GBufL {
  float4 a0, a1, v0, v1, v2;
  float rx, ry, rz; int nj;
};

__device__ __forceinline__ void gather_full(GBuf& b, const float4* __restrict__ srf,
    const float* __restrict__ x_a, const float* __restrict__ x_v, const float* __restrict__ x_d,
    int ei, int end, int part)
{
  b.a0 = float4{0,0,0,0}; b.a1 = float4{0,0,0,0};
  b.v0 = float4{0,0,0,0}; b.v1 = float4{0,0,0,0}; b.v2 = float4{0,0,0,0};
  b.d0 = float2{0,0}; b.d1 = float2{0,0}; b.d2 = float2{0,0}; b.d3 = float2{0,0};
  b.d4 = float2{0,0}; b.d5 = float2{0,0}; b.d6 = float2{0,0}; b.d7 = float2{0,0}; b.d8 = float2{0,0};
  b.rx = 0.0f; b.ry = 0.0f; b.rz = 0.0f;
  if (ei < end) {
    const float4 rv = srf[ei];
    b.rx = rv.x; b.ry = rv.y; b.rz = rv.z;
    const int nj = __float_as_int(rv.w);
    const float4* xa4 = (const float4*)(x_a + (size_t)nj*32);
    b.a0 = xa4[2*part]; b.a1 = xa4[2*part+1];
    const float4* xv4 = (const float4*)(x_v + (size_t)nj*48);
    b.v0 = xv4[3*part]; b.v1 = xv4[3*part+1]; b.v2 = xv4[3*part+2];
    const float2* xd2 = (const float2*)(x_d + (size_t)nj*72) + 9*part;
    b.d0 = xd2[0]; b.d1 = xd2[1]; b.d2 = xd2[2]; b.d3 = xd2[3]; b.d4 = xd2[4];
    b.d5 = xd2[5]; b.d6 = xd2[6]; b.d7 = xd2[7]; b.d8 = xd2[8];
  }
}

__device__ __forceinline__ void gather_lite(GBufL& b, const float4* __restrict__ srf,
    const float* __restrict__ x_a, const float* __restrict__ x_v,
    int ei, int end, int part)
{
  b.a0 = float4{0,0,0,0}; b.a1 = float4{0,0,0,0};
  b.v0 = float4{0,0,0,0}; b.v1 = float4{0,0,0,0}; b.v2 = float4{0,0,0,0};
  b.rx = 0.0f; b.ry = 0.0f; b.rz = 0.0f; b.nj = -1;
  if (ei < end) {
    const float4 rv = srf[ei];
    b.rx = rv.x; b.ry = rv.y; b.rz = rv.z;
    const int nj = __float_as_int(rv.w);
    b.nj = nj;
    const float4* xa4 = (const float4*)(x_a + (size_t)nj*32);
    b.a0 = xa4[2*part]; b.a1 = xa4[2*part+1];
    const float4* xv4 = (const float4*)(x_v + (size_t)nj*48);
    b.v0 = xv4[3*part]; b.v1 = xv4[3*part+1]; b.v2 = xv4[3*part+2];
  }
}

#define DD_FROM(b) { dd[0]=b.d0.x; dd[1]=b.d0.y; dd[2]=b.d1.x; dd[3]=b.d1.y; \
  dd[4]=b.d2.x; dd[5]=b.d2.y; dd[6]=b.d3.x; dd[7]=b.d3.y; dd[8]=b.d4.x; dd[9]=b.d4.y; \
  dd[10]=b.d5.x; dd[11]=b.d5.y; dd[12]=b.d6.x; dd[13]=b.d6.y; dd[14]=b.d7.x; dd[15]=b.d7.y; \
  dd[16]=b.d8.x; dd[17]=b.d8.y; }

// ======================= CSR build =======================
__global__ __launch_bounds__(256) void hist_k(const float* __restrict__ r, const int* __restrict__ src,
                                              int E, int* __restrict__ hist) {
  int e = blockIdx.x * 256 + threadIdx.x;
  if (e >= E) return;
  float rx = r[3*e], ry = r[3*e+1], rz = r[3*e+2];
  float xsq = (rx*rx + ry*ry + rz*rz) * (1.0f/2.5f);
  if (xsq < 1.0f) atomicAdd(&hist[src[e]], 1);
}

__global__ __launch_bounds__(256) void scan_k(int* __restrict__ hist, int Nn, int* __restrict__ row_ptr) {
  __shared__ int part[256];
  const int t = threadIdx.x;
  const int chunk = (Nn + 255) / 256;
  const int i0 = t * chunk;
  int s = 0;
  for (int j = 0; j < chunk; j++) { int i = i0 + j; if (i < Nn) s += hist[i]; }
  part[t] = s;
  __syncthreads();
  for (int off = 1; off < 256; off <<= 1) {
    int v = (t >= off) ? part[t - off] : 0;
    __syncthreads();
    part[t] += v;
    __syncthreads();
  }
  int run = part[t] - s;
  for (int j = 0; j < chunk; j++) {
    int i = i0 + j;
    if (i < Nn) { int h = hist[i]; row_ptr[i] = run; hist[i] = run; run += h; }
  }
  if (t == 255) row_ptr[Nn] = part[255];
}

__global__ __launch_bounds__(256) void scatter_k(const float* __restrict__ r, const int* __restrict__ src,
                                                 const int* __restrict__ dst, int E,
                                                 int* __restrict__ cur, float4* __restrict__ srf) {
  int e = blockIdx.x * 256 + threadIdx.x;
  if (e >= E) return;
  float rx = r[3*e], ry = r[3*e+1], rz = r[3*e+2];
  float xsq = (rx*rx + ry*ry + rz*rz) * (1.0f/2.5f);
  if (xsq < 1.0f) {
    int p = atomicAdd(&cur[src[e]], 1);
    srf[p] = float4{rx, ry, rz, __int_as_float(dst[e])};
  }
}

// ======================= chunk bodies =======================
__device__ __forceinline__ void chunkS(const GBuf& b, const u32* __restrict__ smem,
                                       u32* sc_, u32* se_, int et, int part, int row, int kg,
                                       f4& acc0, f4& acc1)
{
  float dd[18];
  DD_FROM(b);
  Geom g;
  geom_full(b.rx, b.ry, b.rz, g);
  const float h0 = g.h0, h1 = g.h1, h2 = g.h2;
  sc_[et*28 + 4*part + 0] = pk2(b.a0.x, b.a0.y);
  sc_[et*28 + 4*part + 1] = pk2(b.a0.z, b.a0.w);
  sc_[et*28 + 4*part + 2] = pk2(b.a1.x, b.a1.y);
  sc_[et*28 + 4*part + 3] = pk2(b.a1.z, b.a1.w);
  sc_[et*28 + 16 + 2*part]     = pk2(h0*b.v0.x + h1*b.v0.y + h2*b.v0.z, h0*b.v0.w + h1*b.v1.x + h2*b.v1.y);
  sc_[et*28 + 16 + 2*part + 1] = pk2(h0*b.v1.z + h1*b.v1.w + h2*b.v2.x, h0*b.v2.y + h1*b.v2.z + h2*b.v2.w);
  {
    float t0 = h0*dd[0] + h1*dd[3] + h2*dd[6];
    float t1 = h0*dd[1] + h1*dd[4] + h2*dd[7];
    float t2 = h0*dd[2] + h1*dd[5] + h2*dd[8];
    float sa = h0*t0 + h1*t1 + h2*t2;
    float u0 = h0*dd[9]  + h1*dd[12] + h2*dd[15];
    float u1 = h0*dd[10] + h1*dd[13] + h2*dd[16];
    float u2 = h0*dd[11] + h1*dd[14] + h2*dd[17];
    float sb = h0*u0 + h1*u1 + h2*u2;
    sc_[et*28 + 24 + part] = pk2(sa, sb);
  }
  {
    float eA = part==0 ? g.enc[0] : (part==1 ? g.enc[2] : (part==2 ? g.enc[4] : g.enc[6]));
    float eB = part==0 ? g.enc[1] : (part==1 ? g.enc[3] : (part==2 ? g.enc[5] : g.enc[7]));
    se_[et*9 + 2*part]     = pk2(eA, eA);
    se_[et*9 + 2*part + 1] = pk2(eB, eB);
  }
  wave_lds_fence();
  const int lane = row + kg*16;
  #pragma unroll
  for (int s = 0; s < 14; s++) {
    const int m = 4*s + kg;
    const int l = m / 7;
    const int j = m - l*7;
    const uint4 ca = *(const uint4*)&sc_[row*28 + j*4];
    const h8 af = mul_enc(ca, se_[row*9 + l]);
    const h8 b0 = as_h8(*(const uint4*)&smem[(s*64 + lane)*4]);
    const h8 b1 = as_h8(*(const uint4*)&smem[((14 + s)*64 + lane)*4]);
    acc0 = __builtin_amdgcn_mfma_f32_16x16x32_f16(af, b0, acc0, 0, 0, 0);
    acc1 = __builtin_amdgcn_mfma_f32_16x16x32_f16(af, b1, acc1, 0, 0, 0);
  }
}

__device__ __forceinline__ void chunkV(const GBuf& b, const u32* __restrict__ smem,
                                       u32* sx_, u32* sy_, u32* se_, float* sh_,
                                       int et, int part, int row, int kg,
                                       float& nv0, float& nv1, float& nv2)
{
  float dd[18];
  DD_FROM(b);
  Geom g;
  geom_full(b.rx, b.ry, b.rz, g);
  const float h0 = g.h0, h1 = g.h1, h2 = g.h2;
  sx_[et*28 + 4*part + 0] = pk2(b.a0.x, b.a0.y);
  sx_[et*28 + 4*part + 1] = pk2(b.a0.z, b.a0.w);
  sx_[et*28 + 4*part + 2] = pk2(b.a1.x, b.a1.y);
  sx_[et*28 + 4*part + 3] = pk2(b.a1.z, b.a1.w);
  sx_[et*28 + 16 + 2*part]     = pk2(h0*b.v0.x + h1*b.v0.y + h2*b.v0.z, h0*b.v0.w + h1*b.v1.x + h2*b.v1.y);
  sx_[et*28 + 16 + 2*part + 1] = pk2(h0*b.v1.z + h1*b.v1.w + h2*b.v2.x, h0*b.v2.y + h1*b.v2.z + h2*b.v2.w);
  sy_[et*44 + 0*12 + 2*part]     = pk2(b.v0.x, b.v0.w);
  sy_[et*44 + 0*12 + 2*part + 1] = pk2(b.v1.z, b.v2.y);
  sy_[et*44 + 1*12 + 2*part]     = pk2(b.v0.y, b.v1.x);
  sy_[et*44 + 1*12 + 2*part + 1] = pk2(b.v1.w, b.v2.z);
  sy_[et*44 + 2*12 + 2*part]     = pk2(b.v0.z, b.v1.y);
  sy_[et*44 + 2*12 + 2*part + 1] = pk2(b.v2.x, b.v2.w);
  #pragma unroll
  for (int c = 0; c < 3; c++) {
    float a = h0*dd[c]   + h1*dd[3+c]  + h2*dd[6+c];
    float bb = h0*dd[9+c] + h1*dd[12+c] + h2*dd[15+c];
    sy_[et*44 + c*12 + 8 + part] = pk2(a, bb);
  }
  {
    float eA = part==0 ? g.enc[0] : (part==1 ? g.enc[2] : (part==2 ? g.enc[4] : g.enc[6]));
    float eB = part==0 ? g.enc[1] : (part==1 ? g.enc[3] : (part==2 ? g.enc[5] : g.enc[7]));
    se_[et*9 + 2*part]     = pk2(eA, eA);
    se_[et*9 + 2*part + 1] = pk2(eB, eB);
  }
  if (part < 3) {
    float hv = part==0 ? h0 : (part==1 ? h1 : h2);
    sh_[et*3 + part] = hv;
  }
  wave_lds_fence();

  const int lane = row + kg*16;
  f4 accS = {0,0,0,0};
  #pragma unroll
  for (int s = 0; s < 12; s++) {
    const int m = 4*s + kg;
    const int l = m / 6;
    const int j = m - l*6;
    const uint4 ca = *(const uint4*)&sx_[row*28 + j*4];
    const h8 af = mul_enc(ca, se_[row*9 + l]);
    const h8 bf = as_h8(*(const uint4*)&smem[(s*64 + lane)*4]);
    accS = __builtin_amdgcn_mfma_f32_16x16x32_f16(af, bf, accS, 0, 0, 0);
  }
  f4 accA[3], accW[3];
  #pragma unroll
  for (int c = 0; c < 3; c++) { accA[c] = f4{0,0,0,0}; accW[c] = f4{0,0,0,0}; }
  #pragma unroll
  for (int c = 0; c < 3; c++) {
    #pragma unroll
    for (int s = 0; s < 6; s++) {
      const int m = 4*s + kg;
      const int l = m / 3;
      const int j = m - l*3;
      const uint4 ca = *(const uint4*)&sy_[row*44 + c*12 + j*4];
      const h8 af = mul_enc(ca, se_[row*9 + l]);
      const h8 bA = as_h8(*(const uint4*)&smem[3072 + (s*64 + lane)*4]);
      const h8 bW = as_h8(*(const uint4*)&smem[3072 + ((6 + s)*64 + lane)*4]);
      accA[c] = __builtin_amdgcn_mfma_f32_16x16x32_f16(af, bA, accA[c], 0, 0, 0);
      accW[c] = __builtin_amdgcn_mfma_f32_16x16x32_f16(af, bW, accW[c], 0, 0, 0);
    }
  }
  #pragma unroll
  for (int i = 0; i < 4; i++) {
    const int r = kg*4 + i;
    const float rh0 = sh_[r*3], rh1 = sh_[r*3+1], rh2 = sh_[r*3+2];
    const float sv = accS[i];
    const float A0 = accA[0][i], A1 = accA[1][i], A2 = accA[2][i];
    const float W0 = accW[0][i], W1 = accW[1][i], W2 = accW[2][i];
    nv0 += A0 + (rh1*W2 - rh2*W1) + rh0*sv;
    nv1 += A1 + (rh2*W0 - rh0*W2) + rh1*sv;
    nv2 += A2 + (rh0*W1 - rh1*W0) + rh2*sv;
  }
}

__device__ __forceinline__ void chunkD(const GBufL& b, const float* __restrict__ x_d,
                                       const u32* __restrict__ smem,
                                       u32* sa_, u32* sy_, u32* sxp, u32* se_, float* sh_,
                                       int et, int part, int row, int kg,
                                       float (&nd)[9])
{
  float dd[18];
  if (b.nj >= 0) {
    const float2* xd2 = (const float2*)(x_d + (size_t)b.nj*72) + 9*part;
    #pragma unroll
    for (int q = 0; q < 9; q++) { float2 f = xd2[q]; dd[2*q] = f.x; dd[2*q+1] = f.y; }
  } else {
    #pragma unroll
    for (int q = 0; q < 18; q++) dd[q] = 0.0f;
  }
  Geom g;
  geom_full(b.rx, b.ry, b.rz, g);
  const float h0 = g.h0, h1 = g.h1, h2 = g.h2;
  sa_[et*20 + 4*part + 0] = pk2(b.a0.x, b.a0.y);
  sa_[et*20 + 4*part + 1] = pk2(b.a0.z, b.a0.w);
  sa_[et*20 + 4*part + 2] = pk2(b.a1.x, b.a1.y);
  sa_[et*20 + 4*part + 3] = pk2(b.a1.z, b.a1.w);
  sy_[et*44 + 0*12 + 2*part]     = pk2(b.v0.x, b.v0.w);
  sy_[et*44 + 0*12 + 2*part + 1] = pk2(b.v1.z, b.v2.y);
  sy_[et*44 + 1*12 + 2*part]     = pk2(b.v0.y, b.v1.x);
  sy_[et*44 + 1*12 + 2*part + 1] = pk2(b.v1.w, b.v2.z);
  sy_[et*44 + 2*12 + 2*part]     = pk2(b.v0.z, b.v1.y);
  sy_[et*44 + 2*12 + 2*part + 1] = pk2(b.v2.x, b.v2.w);
  #pragma unroll
  for (int c = 0; c < 3; c++) {
    float a = h0*dd[c]   + h1*dd[3+c]  + h2*dd[6+c];
    float bb = h0*dd[9+c] + h1*dd[12+c] + h2*dd[15+c];
    sy_[et*44 + c*12 + 8 + part] = pk2(a, bb);
  }
  #pragma unroll
  for (int ij = 0; ij < 9; ij++)
    sxp[et*44 + ij*4 + part] = pk2(dd[ij], dd[9+ij]);
  {
    float eA = part==0 ? g.enc[0] : (part==1 ? g.enc[2] : (part==2 ? g.enc[4] : g.enc[6]));
    float eB = part==0 ? g.enc[1] : (part==1 ? g.enc[3] : (part==2 ? g.enc[5] : g.enc[7]));
    se_[et*9 + 2*part]     = pk2(eA, eA);
    se_[et*9 + 2*part + 1] = pk2(eB, eB);
  }
  if (part < 3) {
    float hv = part==0 ? h0 : (part==1 ? h1 : h2);
    sh_[et*3 + part] = hv;
  }
  wave_lds_fence();

  const int lane = row + kg*16;
  f4 accSd = {0,0,0,0};
  #pragma unroll
  for (int s = 0; s < 8; s++) {
    const int m = 4*s + kg;
    const int l = m >> 2, j = m & 3;
    const uint4 ca = *(const uint4*)&sa_[row*20 + j*4];
    const h8 af = mul_enc(ca, se_[row*9 + l]);
    const h8 bf = as_h8(*(const uint4*)&smem[(s*64 + lane)*4]);
    accSd = __builtin_amdgcn_mfma_f32_16x16x32_f16(af, bf, accSd, 0, 0, 0);
  }
  f4 accY[3];
  #pragma unroll
  for (int c = 0; c < 3; c++) accY[c] = f4{0,0,0,0};
  #pragma unroll
  for (int c = 0; c < 3; c++) {
    #pragma unroll
    for (int s = 0; s < 6; s++) {
      const int m = 4*s + kg;
      const int l = m / 3;
      const int j = m - l*3;
      const uint4 ca = *(const uint4*)&sy_[row*44 + c*12 + j*4];
      const h8 af = mul_enc(ca, se_[row*9 + l]);
      const h8 bf = as_h8(*(const uint4*)&smem[2048 + (s*64 + lane)*4]);
      accY[c] = __builtin_amdgcn_mfma_f32_16x16x32_f16(af, bf, accY[c], 0, 0, 0);
    }
  }
  f4 accX[9];
  #pragma unroll
  for (int ij = 0; ij < 9; ij++) accX[ij] = f4{0,0,0,0};
  #pragma unroll
  for (int ij = 0; ij < 9; ij++) {
    const uint4 ca = *(const uint4*)&sxp[row*44 + ij*4];
    #pragma unroll
    for (int s = 0; s < 2; s++) {
      const h8 af = mul_enc(ca, se_[row*9 + 4*s + kg]);
      const h8 bf = as_h8(*(const uint4*)&smem[3584 + (s*64 + lane)*4]);
      accX[ij] = __builtin_amdgcn_mfma_f32_16x16x32_f16(af, bf, accX[ij], 0, 0, 0);
    }
  }
  #pragma unroll
  for (int i = 0; i < 4; i++) {
    const int r = kg*4 + i;
    const float rh0 = sh_[r*3], rh1 = sh_[r*3+1], rh2 = sh_[r*3+2];
    const float sd = accSd[i];
    const float A0 = accY[0][i], A1 = accY[1][i], A2 = accY[2][i];
    const float W0 = __shfl_xor(A0, 8, 64);
    const float W1 = __shfl_xor(A1, 8, 64);
    const float W2 = __shfl_xor(A2, 8, 64);
    const float q0 = A0 + (rh1*W2 - rh2*W1) + rh0*sd;
    const float q1 = A1 + (rh2*W0 - rh0*W2) + rh1*sd;
    const float q2 = A2 + (rh0*W1 - rh1*W0) + rh2*sd;
    nd[0] += accX[0][i] + rh0*q0;  nd[1] += accX[1][i] + rh0*q1;  nd[2] += accX[2][i] + rh0*q2;
    nd[3] += accX[3][i] + rh1*q0;  nd[4] += accX[4][i] + rh1*q1;  nd[5] += accX[5][i] + rh1*q2;
    nd[6] += accX[6][i] + rh2*q0;  nd[7] += accX[7][i] + rh2*q1;  nd[8] += accX[8][i] + rh2*q2;
  }
}

// ======================= merged rank-specialized persistent kernel =======================
__global__ __launch_bounds__(256, 3) void msgAll_k(
    const float* __restrict__ x_a, const float* __restrict__ x_v,  const float* __restrict__ x_d,
    const float* __restrict__ P000, const float* __restrict__ P110, const float* __restrict__ P220,
    const float* __restrict__ P011, const float* __restrict__ P101, const float* __restrict__ P121,
    const float* __restrict__ P211, const float* __restrict__ P111,
    const float* __restrict__ P022, const float* __restrict__ P202, const float* __restrict__ P112,
    const float* __restrict__ P222, const float* __restrict__ P212,
    const float4* __restrict__ srf,
    const int* __restrict__ row_ptr, int Nn,
    int gS, int gV,
    float* __restrict__ outA, float* __restrict__ outV, float* __restrict__ outD)
{
  __shared__ __align__(16) u32 smem[11776];
  const int rank = (blockIdx.x < (u32)gS) ? 0 : ((blockIdx.x < (u32)(gS+gV)) ? 1 : 2);

  if (rank == 0) {
    for (int i = threadIdx.x; i < 7168; i += 256) {
      const int p = i & 3, ln = (i >> 2) & 63, rest = i >> 8;
      const int step = rest % 14, tile = rest / 14;
      const int k = step*32 + (ln >> 4)*8 + 2*p;
      const int n = tile*16 + (ln & 15);
      const int l = k / 56, b = k - l*56;
      const int base = n*8 + l;
      float w0, w1;
      if (b < 32)      { w0 = P000[base*32 + b];      w1 = P000[base*32 + b + 1]; }
      else if (b < 48) { w0 = P110[base*16 + (b-32)]; w1 = P110[base*16 + (b-31)]; }
      else             { w0 = P220[base*8  + (b-48)]; w1 = P220[base*8  + (b-47)]; }
      smem[i] = pk2(w0, w1);
    }
  } else if (rank == 1) {
    for (int i = threadIdx.x; i < 6144; i += 256) {
      const int p = i & 3, ln = (i >> 2) & 63;
      const int n = ln & 15, kgq = ln >> 4;
      float w0 = 0.0f, w1 = 0.0f;
      if (i < 3072) {
        const int step = i >> 8;
        const int k = step*32 + kgq*8 + 2*p;
        const int l = k / 48, ch = k - l*48;
        const int base = n*8 + l;
        if (ch < 32) { w0 = P101[base*32 + ch];      w1 = P101[base*32 + ch + 1]; }
        else         { w0 = P211[base*16 + (ch-32)]; w1 = P211[base*16 + (ch-31)]; }
      } else {
        const int iy = i - 3072;
        const int rest = iy >> 8;
        const int step = rest % 6, tile = rest / 6;
        const int k = step*32 + kgq*8 + 2*p;
        const int l = k / 24, ch = k - l*24;
        const int base = n*8 + l;
        if (tile == 0) {
          if (ch < 16) { w0 = P011[base*16 + ch];      w1 = P011[base*16 + ch + 1]; }
          else         { w0 = P121[base*8 + (ch-16)];  w1 = P121[base*8 + (ch-15)]; }
        } else {
          if (ch < 16) { w0 = P111[base*16 + ch];      w1 = P111[base*16 + ch + 1]; }
        }
      }
      smem[i] = pk2(w0, w1);
    }
  } else {
    for (int i = threadIdx.x; i < 4096; i += 256) {
      const int p = i & 3, ln = (i >> 2) & 63;
      const int n16 = ln & 15, kgq = ln >> 4;
      float w0 = 0.0f, w1 = 0.0f;
      if (i < 2048) {
        const int step = i >> 8;
        const int k = step*32 + kgq*8 + 2*p;
        const int l = k >> 5, ch = k & 31;
        if (n16 < 8) { const int b = (n16*8 + l)*32 + ch; w0 = P202[b]; w1 = P202[b+1]; }
      } else if (i < 3584) {
        const int step = (i - 2048) >> 8;
        const int k = step*32 + kgq*8 + 2*p;
        const int l = k / 24, ch = k - l*24;
        if (n16 < 8) {
          if (ch < 16) { const int b = (n16*8 + l)*16 + ch;      w0 = P112[b]; w1 = P112[b+1]; }
          else         { const int b = (n16*8 + l)*8 + (ch-16);  w0 = P222[b]; w1 = P222[b+1]; }
        } else {
          const int d_ = n16 - 8;
          if (ch < 16) { const int b = (d_*8 + l)*16 + ch;       w0 = P212[b]; w1 = P212[b+1]; }
        }
      } else {
        const int step = (i - 3584) >> 8;
        const int k = step*32 + kgq*8 + 2*p;
        const int l = k >> 3, bb = k & 7;
        if (n16 < 8) { const int b = (n16*8 + l)*8 + bb; w0 = P022[b]; w1 = P022[b+1]; }
      }
      smem[i] = pk2(w0, w1);
    }
  }
  __syncthreads();

  const int wv = threadIdx.x >> 6;
  const int lane = threadIdx.x & 63;
  const int et = lane >> 2, part = lane & 3;
  const int row = lane & 15, kg = lane >> 4;

  int bid, nb;
  if (rank == 0)      { bid = blockIdx.x;           nb = gS; }
  else if (rank == 1) { bid = blockIdx.x - gS;      nb = gV; }
  else                { bid = blockIdx.x - gS - gV; nb = (int)gridDim.x - gS - gV; }
  const int W = nb * 4;

  if (rank == 0) {
    u32* sc_ = smem + 7168 + wv*448;
    u32* se_ = smem + 8960 + wv*144;
    int n = bid*4 + wv;
    GBuf A, B;
    int begA = 0, endA = 0, begB = 0, endB = 0;
    if (n < Nn) {
      begA = row_ptr[n]; endA = row_ptr[n+1];
      gather_full(A, srf, x_a, x_v, x_d, begA + et, endA, part);
    }
    while (n < Nn) {
      // ---- half 1: prefetch B for n+W, process A for n ----
      const int nB = n + W;
      if (nB < Nn) {
        begB = row_ptr[nB]; endB = row_ptr[nB+1];
        gather_full(B, srf, x_a, x_v, x_d, begB + et, endB, part);
      }
      {
        f4 acc0 = {0,0,0,0}, acc1 = {0,0,0,0};
        const int nch = (endA - begA + 15) >> 4;
        if (nch > 0) chunkS(A, smem, sc_, se_, et, part, row, kg, acc0, acc1);
        for (int ch = 1; ch < nch; ch++) {
          gather_full(A, srf, x_a, x_v, x_d, begA + ch*16 + et, endA, part);
          chunkS(A, smem, sc_, se_, et, part, row, kg, acc0, acc1);
        }
        float o0 = (acc0[0]+acc0[1])+(acc0[2]+acc0[3]);
        float o1 = (acc1[0]+acc1[1])+(acc1[2]+acc1[3]);
        o0 += __shfl_xor(o0, 16, 64); o0 += __shfl_xor(o0, 32, 64);
        o1 += __shfl_xor(o1, 16, 64); o1 += __shfl_xor(o1, 32, 64);
        if (lane < 16) {
          outA[(size_t)n*32 + lane]      = 0.1f*o0;
          outA[(size_t)n*32 + 16 + lane] = 0.1f*o1;
        }
      }
      n = nB;
      if (n >= Nn) break;
      // ---- half 2: prefetch A for n+W, process B for n ----
      const int nA2 = n + W;
      if (nA2 < Nn) {
        begA = row_ptr[nA2]; endA = row_ptr[nA2+1];
        gather_full(A, srf, x_a, x_v, x_d, begA + et, endA, part);
      }
      {
        f4 acc0 = {0,0,0,0}, acc1 = {0,0,0,0};
        const int nch = (endB - begB + 15) >> 4;
        if (nch > 0) chunkS(B, smem, sc_, se_, et, part, row, kg, acc0, acc1);
        for (int ch = 1; ch < nch; ch++) {
          gather_full(B, srf, x_a, x_v, x_d, begB + ch*16 + et, endB, part);
          chunkS(B, smem, sc_, se_, et, part, row, kg, acc0, acc1);
        }
        float o0 = (acc0[0]+acc0[1])+(acc0[2]+acc0[3]);
        float o1 = (acc1[0]+acc1[1])+(acc1[2]+acc1[3]);
        o0 += __shfl_xor(o0, 16, 64); o0 += __shfl_xor(o0, 32, 64);
        o1 += __shfl_xor(o1, 16, 64); o1 += __shfl_xor(o1, 32, 64);
        if (lane < 16) {
          outA[(size_t)n*32 + lane]      = 0.1f*o0;
          outA[(size_t)n*32 + 16 + lane] = 0.1f*o1;
        }
      }
      n = nA2;
    }
  } else if (rank == 1) {
    u32* sx_ = smem + 6144 + wv*448;
    u32* sy_ = smem + 7936 + wv*704;
    u32* se_ = smem + 10752 + wv*144;
    float* sh_ = (float*)(smem + 11328) + wv*48;
    int n = bid*4 + wv;
    GBuf A, B;
    int begA = 0, endA = 0, begB = 0, endB = 0;
    if (n < Nn) {
      begA = row_ptr[n]; endA = row_ptr[n+1];
      gather_full(A, srf, x_a, x_v, x_d, begA + et, endA, part);
    }
    while (n < Nn) {
      const int nB = n + W;
      if (nB < Nn) {
        begB = row_ptr[nB]; endB = row_ptr[nB+1];
        gather_full(B, srf, x_a, x_v, x_d, begB + et, endB, part);
      }
      {
        float nv0 = 0.f, nv1 = 0.f, nv2 = 0.f;
        const int nch = (endA - begA + 15) >> 4;
        if (nch > 0) chunkV(A, smem, sx_, sy_, se_, sh_, et, part, row, kg, nv0, nv1, nv2);
        for (int ch = 1; ch < nch; ch++) {
          gather_full(A, srf, x_a, x_v, x_d, begA + ch*16 + et, endA, part);
          chunkV(A, smem, sx_, sy_, se_, sh_, et, part, row, kg, nv0, nv1, nv2);
        }
        nv0 += __shfl_xor(nv0, 16, 64); nv0 += __shfl_xor(nv0, 32, 64);
        nv1 += __shfl_xor(nv1, 16, 64); nv1 += __shfl_xor(nv1, 32, 64);
        nv2 += __shfl_xor(nv2, 16, 64); nv2 += __shfl_xor(nv2, 32, 64);
        if (lane < 16) {
          float* o = outV + (size_t)n*48 + lane*3;
          o[0] = 0.1f*nv0; o[1] = 0.1f*nv1; o[2] = 0.1f*nv2;
        }
      }
      n = nB;
      if (n >= Nn) break;
      const int nA2 = n + W;
      if (nA2 < Nn) {
        begA = row_ptr[nA2]; endA = row_ptr[nA2+1];
        gather_full(A, srf, x_a, x_v, x_d, begA + et, endA, part);
      }
      {
        float nv0 = 0.f, nv1 = 0.f, nv2 = 0.f;
        const int nch = (endB - begB + 15) >> 4;
        if (nch > 0) chunkV(B, smem, sx_, sy_, se_, sh_, et, part, row, kg, nv0, nv1, nv2);
        for (int ch = 1; ch < nch; ch++) {
          gather_full(B, srf, x_a, x_v, x_d, begB + ch*16 + et, endB, part);
          chunkV(B, smem, sx_, sy_, se_, sh_, et, part, row, kg, nv0, nv1, nv2);
        }
        nv0 += __shfl_xor(nv0, 16, 64); nv0 += __shfl_xor(nv0, 32, 64);
        nv1 += __shfl_xor(nv1, 16, 64); nv1 += __shfl_xor(nv1, 32, 64);
        nv2 += __shfl_xor(nv2, 16, 64); nv2 += __shfl_xor(nv2, 32, 64);
        if (lane < 16) {
          float* o = outV + (size_t)n*48 + lane*3;
          o[0] = 0.1f*nv0; o[1] = 0.1f*nv1; o[2] = 0.1f*nv2;
        }
      }
      n = nA2;
    }
  } else {
    u32* sa_ = smem + 4096 + wv*320;
    u32* sy_ = smem + 5376 + wv*704;
    u32* sxp = smem + 8192 + wv*704;
    u32* se_ = smem + 11008 + wv*144;
    float* sh_ = (float*)(smem + 11584) + wv*48;
    int n = bid*4 + wv;
    GBufL A, B;
    int begA = 0, endA = 0, begB = 0, endB = 0;
    if (n < Nn) {
      begA = row_ptr[n]; endA = row_ptr[n+1];
      gather_lite(A, srf, x_a, x_v, begA + et, endA, part);
    }
    while (n < Nn) {
      const int nB = n + W;
      if (nB < Nn) {
        begB = row_ptr[nB]; endB = row_ptr[nB+1];
        gather_lite(B, srf, x_a, x_v, begB + et, endB, part);
      }
      {
        float nd[9] = {0,0,0,0,0,0,0,0,0};
        const int nch = (endA - begA + 15) >> 4;
        if (nch > 0) chunkD(A, x_d, smem, sa_, sy_, sxp, se_, sh_, et, part, row, kg, nd);
        for (int ch = 1; ch < nch; ch++) {
          gather_lite(A, srf, x_a, x_v, begA + ch*16 + et, endA, part);
          chunkD(A, x_d, smem, sa_, sy_, sxp, se_, sh_, et, part, row, kg, nd);
        }
        #pragma unroll
        for (int k = 0; k < 9; k++) {
          nd[k] += __shfl_xor(nd[k], 16, 64);
          nd[k] += __shfl_xor(nd[k], 32, 64);
        }
        if (lane < 8) {
          float* o = outD + (size_t)n*72 + lane*9;
          #pragma unroll
          for (int k = 0; k < 9; k++) o[k] = 0.1f*nd[k];
        }
      }
      n = nB;
      if (n >= Nn) break;
      const int nA2 = n + W;
      if (nA2 < Nn) {
        begA = row_ptr[nA2]; endA = row_ptr[nA2+1];
        gather_lite(A, srf, x_a, x_v, begA + et, endA, part);
      }
      {
        float nd[9] = {0,0,0,0,0,0,0,0,0};
        const int nch = (endB - begB + 15) >> 4;
        if (nch > 0) chunkD(B, x_d, smem, sa_, sy_, sxp, se_, sh_, et, part, row, kg, nd);
        for (int ch = 1; ch < nch; ch++) {
          gather_lite(B, srf, x_a, x_v, begB + ch*16 + et, endB, part);
          chunkD(B, x_d, smem, sa_, sy_, sxp, se_, sh_, et, part, row, kg, nd);
        }
        #pragma unroll
        for (int k = 0; k < 9; k++) {
          nd[k] += __shfl_xor(nd[k], 16, 64);
          nd[k] += __shfl_xor(nd[k], 32, 64);
        }
        if (lane < 8) {
          float* o = outD + (size_t)n*72 + lane*9;
          #pragma unroll
          for (int k = 0; k < 9; k++) o[k] = 0.1f*nd[k];
        }
      }
      n = nA2;
    }
  }
}

// ======================= scalar fallback (insurance only) =======================
__global__ __launch_bounds__(256) void fallback_all(
    const float* __restrict__ r_ij, const float* __restrict__ x_a,
    const float* __restrict__ x_v,  const float* __restrict__ x_d,
    const float* __restrict__ P000, const float* __restrict__ P110, const float* __restrict__ P220,
    const float* __restrict__ P011, const float* __restrict__ P101, const float* __restrict__ P121,
    const float* __restrict__ P211, const float* __restrict__ P111,
    const float* __restrict__ P022, const float* __restrict__ P202, const float* __restrict__ P112,
    const float* __restrict__ P222, const float* __restrict__ P212,
    const int* __restrict__ src, const int* __restrict__ dst, int E,
    float* __restrict__ outA, float* __restrict__ outV, float* __restrict__ outD)
{
  const int e = blockIdx.x*256 + threadIdx.x;
  if (e >= E) return;
  Geom g;
  if (!geom_of(r_ij, e, g)) return;
  const int nj = dst[e], ni = src[e];
  const float* xa = x_a + (size_t)nj*32;
  const float* xv = x_v + (size_t)nj*48;
  const float* xd = x_d + (size_t)nj*72;
  float V0[16],V1[16],V2[16],s1[16],T0[8],T1[8],T2[8],s2[8];
  for (int b = 0; b < 16; b++) {
    V0[b]=xv[3*b]; V1[b]=xv[3*b+1]; V2[b]=xv[3*b+2];
    s1[b]=g.h0*V0[b]+g.h1*V1[b]+g.h2*V2[b];
  }
  for (int b = 0; b < 8; b++) {
    const float* m = xd + 9*b;
    T0[b]=g.h0*m[0]+g.h1*m[3]+g.h2*m[6];
    T1[b]=g.h0*m[1]+g.h1*m[4]+g.h2*m[7];
    T2[b]=g.h0*m[2]+g.h1*m[5]+g.h2*m[8];
    s2[b]=g.h0*T0[b]+g.h1*T1[b]+g.h2*T2[b];
  }
  for (int a = 0; a < 32; a++) {
    float acc = 0;
    for (int l = 0; l < 8; l++) {
      float u = 0;
      for (int b = 0; b < 32; b++) u += P000[(a*8+l)*32+b]*xa[b];
      for (int b = 0; b < 16; b++) u += P110[(a*8+l)*16+b]*s1[b];
      for (int b = 0; b < 8;  b++) u += P220[(a*8+l)*8+b]*s2[b];
      acc += g.enc[l]*u;
    }
    atomicAdd(outA + (size_t)ni*32 + a, 0.1f*acc);
  }
  for (int v = 0; v < 16; v++) {
    float sv=0,A0=0,A1=0,A2=0,W0=0,W1=0,W2=0;
    for (int l = 0; l < 8; l++) {
      const float el = g.enc[l];
      float u=0;
      for (int b=0;b<32;b++) u += P101[(v*8+l)*32+b]*xa[b];
      for (int b=0;b<16;b++) u += P211[(v*8+l)*16+b]*s1[b];
      sv += el*u;
      float a0=0,a1=0,a2=0,w0=0,w1=0,w2=0;
      for (int b=0;b<16;b++){float p=P011[(v*8+l)*16+b]; a0+=p*V0[b];a1+=p*V1[b];a2+=p*V2[b];}
      for (int b=0;b<8;b++){float p=P121[(v*8+l)*8+b]; a0+=p*T0[b];a1+=p*T1[b];a2+=p*T2[b];}
      for (int b=0;b<16;b++){float p=P111[(v*8+l)*16+b]; w0+=p*V0[b];w1+=p*V1[b];w2+=p*V2[b];}
      A0+=el*a0;A1+=el*a1;A2+=el*a2;W0+=el*w0;W1+=el*w1;W2+=el*w2;
    }
    float* o = outV + (size_t)ni*48 + v*3;
    atomicAdd(o+0, 0.1f*(A0 + (g.h1*W2-g.h2*W1) + g.h0*sv));
    atomicAdd(o+1, 0.1f*(A1 + (g.h2*W0-g.h0*W2) + g.h1*sv));
    atomicAdd(o+2, 0.1f*(A2 + (g.h0*W1-g.h1*W0) + g.h2*sv));
  }
  const float hh[3]={g.h0,g.h1,g.h2};
  for (int d = 0; d < 8; d++) {
    float sd=0,A0=0,A1=0,A2=0,W0=0,W1=0,W2=0;
    float w[8]={0,0,0,0,0,0,0,0};
    for (int l = 0; l < 8; l++) {
      const float el = g.enc[l];
      float u=0;
      for (int b=0;b<32;b++) u += P202[(d*8+l)*32+b]*xa[b];
      sd += el*u;
      float a0=0,a1=0,a2=0,w0=0,w1=0,w2=0;
      for (int b=0;b<16;b++){float p=P112[(d*8+l)*16+b]; a0+=p*V0[b];a1+=p*V1[b];a2+=p*V2[b];}
      for (int b=0;b<8;b++){float p=P222[(d*8+l)*8+b]; a0+=p*T0[b];a1+=p*T1[b];a2+=p*T2[b];}
      for (int b=0;b<16;b++){float p=P212[(d*8+l)*16+b]; w0+=p*V0[b];w1+=p*V1[b];w2+=p*V2[b];}
      A0+=el*a0;A1+=el*a1;A2+=el*a2;W0+=el*w0;W1+=el*w1;W2+=el*w2;
      for (int b=0;b<8;b++) w[b]+=el*P022[(d*8+l)*8+b];
    }
    const float q[3] = { A0+(g.h1*W2-g.h2*W1)+g.h0*sd,
                         A1+(g.h2*W0-g.h0*W2)+g.h1*sd,
                         A2+(g.h0*W1-g.h1*W0)+g.h2*sd };
    float* o = outD + (size_t)ni*72 + d*9;
    for (int ii = 0; ii < 3; ii++)
      for (int jj = 0; jj < 3; jj++) {
        float acc = 0;
        for (int b = 0; b < 8; b++) acc += w[b]*xd[9*b + ii*3 + jj];
        atomicAdd(o + ii*3 + jj, 0.1f*(acc + hh[ii]*q[jj]));
      }
  }
}

extern "C" void kernel_launch(void* const* d_in, const int* in_sizes, int n_in,
                              void* d_out, int out_size, void* d_ws, size_t ws_size,
                              hipStream_t stream) {
  const float* r_ij = (const float*)d_in[0];
  const float* x_a  = (const float*)d_in[1];
  const float* x_v  = (const float*)d_in[2];
  const float* x_d  = (const float*)d_in[3];
  const float* P000 = (const float*)d_in[4];
  const float* P110 = (const float*)d_in[5];
  const float* P220 = (const float*)d_in[6];
  const float* P011 = (const float*)d_in[7];
  const float* P101 = (const float*)d_in[8];
  const float* P121 = (const float*)d_in[9];
  const float* P211 = (const float*)d_in[10];
  const float* P111 = (const float*)d_in[11];
  const float* P022 = (const float*)d_in[12];
  const float* P202 = (const float*)d_in[13];
  const float* P112 = (const float*)d_in[14];
  const float* P222 = (const float*)d_in[15];
  const float* P212 = (const float*)d_in[16];
  const int* src = (const int*)d_in[17];
  const int* dst = (const int*)d_in[18];

  const int E  = in_sizes[17];
  const int Nn = in_sizes[1] / 32;
  float* out  = (float*)d_out;
  float* outA = out;
  float* outV = out + (size_t)Nn*32;
  float* outD = out + (size_t)Nn*80;

  // ws layout: srf (E x float4, 16B aligned at base) | hist (N int) | row_ptr (N+1 int)
  const size_t need = 16ull*(size_t)E + 4ull*(2ull*(size_t)Nn + 1);
  if (ws_size >= need) {
    float4* srf  = (float4*)d_ws;
    int* hist    = (int*)(srf + E);
    int* row_ptr = hist + Nn;
    hipMemsetAsync(hist, 0, (size_t)Nn*sizeof(int), stream);
    hist_k   <<<(E + 255)/256, 256, 0, stream>>>(r_ij, src, E, hist);
    scan_k   <<<1, 256, 0, stream>>>(hist, Nn, row_ptr);
    scatter_k<<<(E + 255)/256, 256, 0, stream>>>(r_ij, src, dst, E, hist, srf);

    const int gS = 192, gV = 288, gD = 288;   // 768 blocks = 3/CU (47KB LDS)
    msgAll_k<<<gS + gV + gD, 256, 0, stream>>>(x_a, x_v, x_d,
        P000, P110, P220, P011, P101, P121, P211, P111,
        P022, P202, P112, P222, P212,
        srf, row_ptr, Nn, gS, gV, outA, outV, outD);
  } else {
    hipMemsetAsync(d_out, 0, (size_t)out_size * sizeof(float), stream);
    fallback_all<<<(E + 255)/256, 256, 0, stream>>>(r_ij, x_a, x_v, x_d,
        P000, P110, P220, P011, P101, P121, P211, P111,
        P022, P202, P112, P222, P212, src, dst, E, outA, outV, outD);
  }
}

// Round 14
// 142.457 us; speedup vs baseline: 2.5097x; 2.5097x over previous
//
#include <hip/hip_runtime.h>

#define PI_F 3.14159265358979323846f

typedef _Float16 h8 __attribute__((ext_vector_type(8)));
typedef _Float16 h2v __attribute__((ext_vector_type(2)));
typedef float f4 __attribute__((ext_vector_type(4)));
typedef unsigned int u32;

struct Geom { float enc[8]; float h0, h1, h2; };

__device__ __forceinline__ bool geom_of(const float* __restrict__ r, int e, Geom& g) {
  const float rx = r[3*e], ry = r[3*e+1], rz = r[3*e+2];
  const float xsq = (rx*rx + ry*ry + rz*rz) * (1.0f/2.5f);
  const float cut = 1.0f - xsq;
  if (cut <= 0.0f) return false;
  const float c1 = cosf(PI_F * sqrtf(xsq));
  g.enc[0] = cut; g.enc[1] = c1*cut;
  float cp = 1.0f, cc = c1;
  #pragma unroll
  for (int n = 2; n < 8; n++) { float cn = 2.0f*c1*cc - cp; cp = cc; cc = cn; g.enc[n] = cn*cut; }
  const float s = 7.0f/2.5f;
  const float yx = rx*s, yy = ry*s, yz = rz*s;
  const float inv = rsqrtf(1.0f + yx*yx + yy*yy + yz*yz);
  g.h0 = yx*inv; g.h1 = yy*inv; g.h2 = yz*inv;
  return true;
}

__device__ __forceinline__ u32 pk2(float a, float b) {
  union { h2v h; u32 u; } r;
  r.h.x = (_Float16)a; r.h.y = (_Float16)b;
  return r.u;
}

__device__ __forceinline__ h8 mul_enc(uint4 c, u32 e) {
  union { uint4 u; h2v p[4]; } C; C.u = c;
  union { u32 u; h2v h; } E; E.u = e;
  union { h2v p[4]; h8 v; } R;
  #pragma unroll
  for (int i = 0; i < 4; i++) R.p[i] = C.p[i] * E.h;
  return R.v;
}

__device__ __forceinline__ h8 as_h8(uint4 c) { union { uint4 u; h8 v; } r; r.u = c; return r.v; }

__device__ __forceinline__ void wave_lds_fence() {
  asm volatile("s_waitcnt lgkmcnt(0)" ::: "memory");
  __builtin_amdgcn_sched_barrier(0);
}

// ======================= CSR build =======================
__global__ __launch_bounds__(256) void hist_k(const float* __restrict__ r, const int* __restrict__ src,
                                              int E, int* __restrict__ hist) {
  int e = blockIdx.x * 256 + threadIdx.x;
  if (e >= E) return;
  float rx = r[3*e], ry = r[3*e+1], rz = r[3*e+2];
  float xsq = (rx*rx + ry*ry + rz*rz) * (1.0f/2.5f);
  if (xsq < 1.0f) atomicAdd(&hist[src[e]], 1);
}

// single-block scan; LDS-staged coalesced path for Nn <= 20480
__global__ __launch_bounds__(1024) void scan_k(int* __restrict__ hist, int Nn, int* __restrict__ row_ptr) {
  __shared__ int sh[20480];
  __shared__ int part[1024];
  const int t = threadIdx.x;
  if (Nn <= 20480) {
    for (int i = t; i < Nn; i += 1024) sh[i] = hist[i];
    __syncthreads();
    const int chunk = (Nn + 1023) / 1024;
    const int i0 = t * chunk;
    int s = 0;
    for (int j = 0; j < chunk; j++) { int i = i0 + j; if (i < Nn) s += sh[i]; }
    part[t] = s;
    __syncthreads();
    for (int off = 1; off < 1024; off <<= 1) {
      int v = (t >= off) ? part[t - off] : 0;
      __syncthreads();
      part[t] += v;
      __syncthreads();
    }
    int run = part[t] - s;   // exclusive prefix of this thread's chunk
    for (int j = 0; j < chunk; j++) {
      int i = i0 + j;
      if (i < Nn) { int h = sh[i]; sh[i] = run; run += h; }
    }
    __syncthreads();
    for (int i = t; i < Nn; i += 1024) { int v = sh[i]; row_ptr[i] = v; hist[i] = v; }
    if (t == 1023) row_ptr[Nn] = part[1023];
  } else {
    // fallback: global-memory chunk scan (correctness path for large Nn)
    const int chunk = (Nn + 1023) / 1024;
    const int i0 = t * chunk;
    int s = 0;
    for (int j = 0; j < chunk; j++) { int i = i0 + j; if (i < Nn) s += hist[i]; }
    part[t] = s;
    __syncthreads();
    for (int off = 1; off < 1024; off <<= 1) {
      int v = (t >= off) ? part[t - off] : 0;
      __syncthreads();
      part[t] += v;
      __syncthreads();
    }
    int run = part[t] - s;
    for (int j = 0; j < chunk; j++) {
      int i = i0 + j;
      if (i < Nn) { int h = hist[i]; row_ptr[i] = run; hist[i] = run; run += h; }
    }
    if (t == 1023) row_ptr[Nn] = part[1023];
  }
}

__global__ __launch_bounds__(256) void scatter_k(const float* __restrict__ r, const int* __restrict__ src,
                                                 int E, int* __restrict__ cur, int* __restrict__ sorted) {
  int e = blockIdx.x * 256 + threadIdx.x;
  if (e >= E) return;
  float rx = r[3*e], ry = r[3*e+1], rz = r[3*e+2];
  float xsq = (rx*rx + ry*ry + rz*rz) * (1.0f/2.5f);
  if (xsq < 1.0f) {
    int p = atomicAdd(&cur[src[e]], 1);
    sorted[p] = e;
  }
}

// ======================= merged rank-specialized persistent kernel (R10, verbatim) =======================
// blocks [0,gS): psi_a ; [gS,gS+gV): psi_v ; rest: psi_d. 47KB LDS -> 3 blocks/CU.
__global__ __launch_bounds__(256, 3) void msgAll_k(
    const float* __restrict__ r_ij, const float* __restrict__ x_a,
    const float* __restrict__ x_v,  const float* __restrict__ x_d,
    const float* __restrict__ P000, const float* __restrict__ P110, const float* __restrict__ P220,
    const float* __restrict__ P011, const float* __restrict__ P101, const float* __restrict__ P121,
    const float* __restrict__ P211, const float* __restrict__ P111,
    const float* __restrict__ P022, const float* __restrict__ P202, const float* __restrict__ P112,
    const float* __restrict__ P222, const float* __restrict__ P212,
    const int* __restrict__ dst,
    const int* __restrict__ row_ptr, const int* __restrict__ sorted, int Nn,
    int gS, int gV,
    float* __restrict__ outA, float* __restrict__ outV, float* __restrict__ outD)
{
  __shared__ __align__(16) u32 smem[11776];
  const int rank = (blockIdx.x < (u32)gS) ? 0 : ((blockIdx.x < (u32)(gS+gV)) ? 1 : 2);

  if (rank == 0) {
    for (int i = threadIdx.x; i < 7168; i += 256) {
      const int p = i & 3, ln = (i >> 2) & 63, rest = i >> 8;
      const int step = rest % 14, tile = rest / 14;
      const int k = step*32 + (ln >> 4)*8 + 2*p;
      const int n = tile*16 + (ln & 15);
      const int l = k / 56, b = k - l*56;
      const int base = n*8 + l;
      float w0, w1;
      if (b < 32)      { w0 = P000[base*32 + b];      w1 = P000[base*32 + b + 1]; }
      else if (b < 48) { w0 = P110[base*16 + (b-32)]; w1 = P110[base*16 + (b-31)]; }
      else             { w0 = P220[base*8  + (b-48)]; w1 = P220[base*8  + (b-47)]; }
      smem[i] = pk2(w0, w1);
    }
  } else if (rank == 1) {
    for (int i = threadIdx.x; i < 6144; i += 256) {
      const int p = i & 3, ln = (i >> 2) & 63;
      const int n = ln & 15, kgq = ln >> 4;
      float w0 = 0.0f, w1 = 0.0f;
      if (i < 3072) {
        const int step = i >> 8;
        const int k = step*32 + kgq*8 + 2*p;
        const int l = k / 48, ch = k - l*48;
        const int base = n*8 + l;
        if (ch < 32) { w0 = P101[base*32 + ch];      w1 = P101[base*32 + ch + 1]; }
        else         { w0 = P211[base*16 + (ch-32)]; w1 = P211[base*16 + (ch-31)]; }
      } else {
        const int iy = i - 3072;
        const int rest = iy >> 8;
        const int step = rest % 6, tile = rest / 6;
        const int k = step*32 + kgq*8 + 2*p;
        const int l = k / 24, ch = k - l*24;
        const int base = n*8 + l;
        if (tile == 0) {
          if (ch < 16) { w0 = P011[base*16 + ch];      w1 = P011[base*16 + ch + 1]; }
          else         { w0 = P121[base*8 + (ch-16)];  w1 = P121[base*8 + (ch-15)]; }
        } else {
          if (ch < 16) { w0 = P111[base*16 + ch];      w1 = P111[base*16 + ch + 1]; }
        }
      }
      smem[i] = pk2(w0, w1);
    }
  } else {
    for (int i = threadIdx.x; i < 4096; i += 256) {
      const int p = i & 3, ln = (i >> 2) & 63;
      const int n16 = ln & 15, kgq = ln >> 4;
      float w0 = 0.0f, w1 = 0.0f;
      if (i < 2048) {
        const int step = i >> 8;
        const int k = step*32 + kgq*8 + 2*p;
        const int l = k >> 5, ch = k & 31;
        if (n16 < 8) { const int b = (n16*8 + l)*32 + ch; w0 = P202[b]; w1 = P202[b+1]; }
      } else if (i < 3584) {
        const int step = (i - 2048) >> 8;
        const int k = step*32 + kgq*8 + 2*p;
        const int l = k / 24, ch = k - l*24;
        if (n16 < 8) {
          if (ch < 16) { const int b = (n16*8 + l)*16 + ch;      w0 = P112[b]; w1 = P112[b+1]; }
          else         { const int b = (n16*8 + l)*8 + (ch-16);  w0 = P222[b]; w1 = P222[b+1]; }
        } else {
          const int d_ = n16 - 8;
          if (ch < 16) { const int b = (d_*8 + l)*16 + ch;       w0 = P212[b]; w1 = P212[b+1]; }
        }
      } else {
        const int step = (i - 3584) >> 8;
        const int k = step*32 + kgq*8 + 2*p;
        const int l = k >> 3, bb = k & 7;
        if (n16 < 8) { const int b = (n16*8 + l)*8 + bb; w0 = P022[b]; w1 = P022[b+1]; }
      }
      smem[i] = pk2(w0, w1);
    }
  }
  __syncthreads();

  const int wv = threadIdx.x >> 6;
  const int lane = threadIdx.x & 63;
  const int et = lane >> 2, part = lane & 3;
  const int row = lane & 15, kg = lane >> 4;

  int bid, nb;
  if (rank == 0)      { bid = blockIdx.x;           nb = gS; }
  else if (rank == 1) { bid = blockIdx.x - gS;      nb = gV; }
  else                { bid = blockIdx.x - gS - gV; nb = (int)gridDim.x - gS - gV; }
  const int W = nb * 4;

  if (rank == 0) {
    u32* sc_ = smem + 7168 + wv*448;
    u32* se_ = smem + 8960 + wv*144;
    for (int n = bid*4 + wv; n < Nn; n += W) {
      const int beg = row_ptr[n], end = row_ptr[n+1];
      const int nch = (end - beg + 15) >> 4;
      f4 acc0 = {0,0,0,0}, acc1 = {0,0,0,0};

      for (int ch = 0; ch < nch; ch++) {
        const int ei = beg + ch*16 + et;
        const int e = (ei < end) ? sorted[ei] : -1;
        Geom g = {};
        const bool ok = (e >= 0) && geom_of(r_ij, e, g);
        float4 a0={0,0,0,0}, a1={0,0,0,0}, v0={0,0,0,0}, v1={0,0,0,0}, v2={0,0,0,0};
        float dd[18] = {0,0,0,0,0,0,0,0,0,0,0,0,0,0,0,0,0,0};
        if (ok) {
          const int nj = dst[e];
          const float4* xa4 = (const float4*)(x_a + (size_t)nj*32);
          a0 = xa4[2*part]; a1 = xa4[2*part+1];
          const float4* xv4 = (const float4*)(x_v + (size_t)nj*48);
          v0 = xv4[3*part]; v1 = xv4[3*part+1]; v2 = xv4[3*part+2];
          const float2* xd2 = (const float2*)(x_d + (size_t)nj*72) + 9*part;
          #pragma unroll
          for (int q = 0; q < 9; q++) { float2 f = xd2[q]; dd[2*q] = f.x; dd[2*q+1] = f.y; }
        }
        const float h0 = g.h0, h1 = g.h1, h2 = g.h2;
        sc_[et*28 + 4*part + 0] = pk2(a0.x, a0.y);
        sc_[et*28 + 4*part + 1] = pk2(a0.z, a0.w);
        sc_[et*28 + 4*part + 2] = pk2(a1.x, a1.y);
        sc_[et*28 + 4*part + 3] = pk2(a1.z, a1.w);
        sc_[et*28 + 16 + 2*part]     = pk2(h0*v0.x + h1*v0.y + h2*v0.z, h0*v0.w + h1*v1.x + h2*v1.y);
        sc_[et*28 + 16 + 2*part + 1] = pk2(h0*v1.z + h1*v1.w + h2*v2.x, h0*v2.y + h1*v2.z + h2*v2.w);
        {
          float t0 = h0*dd[0] + h1*dd[3] + h2*dd[6];
          float t1 = h0*dd[1] + h1*dd[4] + h2*dd[7];
          float t2 = h0*dd[2] + h1*dd[5] + h2*dd[8];
          float sa = h0*t0 + h1*t1 + h2*t2;
          float u0 = h0*dd[9]  + h1*dd[12] + h2*dd[15];
          float u1 = h0*dd[10] + h1*dd[13] + h2*dd[16];
          float u2 = h0*dd[11] + h1*dd[14] + h2*dd[17];
          float sb = h0*u0 + h1*u1 + h2*u2;
          sc_[et*28 + 24 + part] = pk2(sa, sb);
        }
        {
          float eA = part==0 ? g.enc[0] : (part==1 ? g.enc[2] : (part==2 ? g.enc[4] : g.enc[6]));
          float eB = part==0 ? g.enc[1] : (part==1 ? g.enc[3] : (part==2 ? g.enc[5] : g.enc[7]));
          se_[et*9 + 2*part]     = pk2(eA, eA);
          se_[et*9 + 2*part + 1] = pk2(eB, eB);
        }
        wave_lds_fence();
        #pragma unroll
        for (int s = 0; s < 14; s++) {
          const int m = 4*s + kg;
          const int l = m / 7;
          const int j = m - l*7;
          const uint4 ca = *(const uint4*)&sc_[row*28 + j*4];
          const h8 af = mul_enc(ca, se_[row*9 + l]);
          const h8 b0 = as_h8(*(const uint4*)&smem[(s*64 + lane)*4]);
          const h8 b1 = as_h8(*(const uint4*)&smem[((14 + s)*64 + lane)*4]);
          acc0 = __builtin_amdgcn_mfma_f32_16x16x32_f16(af, b0, acc0, 0, 0, 0);
          acc1 = __builtin_amdgcn_mfma_f32_16x16x32_f16(af, b1, acc1, 0, 0, 0);
        }
      }

      float o0 = (acc0[0]+acc0[1])+(acc0[2]+acc0[3]);
      float o1 = (acc1[0]+acc1[1])+(acc1[2]+acc1[3]);
      o0 += __shfl_xor(o0, 16, 64); o0 += __shfl_xor(o0, 32, 64);
      o1 += __shfl_xor(o1, 16, 64); o1 += __shfl_xor(o1, 32, 64);
      if (lane < 16) {
        outA[(size_t)n*32 + lane]      = 0.1f*o0;
        outA[(size_t)n*32 + 16 + lane] = 0.1f*o1;
      }
    }
  } else if (rank == 1) {
    u32* sx_ = smem + 6144 + wv*448;
    u32* sy_ = smem + 7936 + wv*704;
    u32* se_ = smem + 10752 + wv*144;
    float* sh_ = (float*)(smem + 11328) + wv*48;
    for (int n = bid*4 + wv; n < Nn; n += W) {
      const int beg = row_ptr[n], end = row_ptr[n+1];
      const int nch = (end - beg + 15) >> 4;
      float nv0 = 0.f, nv1 = 0.f, nv2 = 0.f;

      for (int ch = 0; ch < nch; ch++) {
        const int ei = beg + ch*16 + et;
        const int e = (ei < end) ? sorted[ei] : -1;
        Geom g = {};
        const bool ok = (e >= 0) && geom_of(r_ij, e, g);
        float4 a0={0,0,0,0}, a1={0,0,0,0}, v0={0,0,0,0}, v1={0,0,0,0}, v2={0,0,0,0};
        float dd[18] = {0,0,0,0,0,0,0,0,0,0,0,0,0,0,0,0,0,0};
        if (ok) {
          const int nj = dst[e];
          const float4* xa4 = (const float4*)(x_a + (size_t)nj*32);
          a0 = xa4[2*part]; a1 = xa4[2*part+1];
          const float4* xv4 = (const float4*)(x_v + (size_t)nj*48);
          v0 = xv4[3*part]; v1 = xv4[3*part+1]; v2 = xv4[3*part+2];
          const float2* xd2 = (const float2*)(x_d + (size_t)nj*72) + 9*part;
          #pragma unroll
          for (int q = 0; q < 9; q++) { float2 f = xd2[q]; dd[2*q] = f.x; dd[2*q+1] = f.y; }
        }
        const float h0 = g.h0, h1 = g.h1, h2 = g.h2;
        sx_[et*28 + 4*part + 0] = pk2(a0.x, a0.y);
        sx_[et*28 + 4*part + 1] = pk2(a0.z, a0.w);
        sx_[et*28 + 4*part + 2] = pk2(a1.x, a1.y);
        sx_[et*28 + 4*part + 3] = pk2(a1.z, a1.w);
        sx_[et*28 + 16 + 2*part]     = pk2(h0*v0.x + h1*v0.y + h2*v0.z, h0*v0.w + h1*v1.x + h2*v1.y);
        sx_[et*28 + 16 + 2*part + 1] = pk2(h0*v1.z + h1*v1.w + h2*v2.x, h0*v2.y + h1*v2.z + h2*v2.w);
        sy_[et*44 + 0*12 + 2*part]     = pk2(v0.x, v0.w);
        sy_[et*44 + 0*12 + 2*part + 1] = pk2(v1.z, v2.y);
        sy_[et*44 + 1*12 + 2*part]     = pk2(v0.y, v1.x);
        sy_[et*44 + 1*12 + 2*part + 1] = pk2(v1.w, v2.z);
        sy_[et*44 + 2*12 + 2*part]     = pk2(v0.z, v1.y);
        sy_[et*44 + 2*12 + 2*part + 1] = pk2(v2.x, v2.w);
        #pragma unroll
        for (int c = 0; c < 3; c++) {
          float a = h0*dd[c]   + h1*dd[3+c]  + h2*dd[6+c];
          float b = h0*dd[9+c] + h1*dd[12+c] + h2*dd[15+c];
          sy_[et*44 + c*12 + 8 + part] = pk2(a, b);
        }
        {
          float eA = part==0 ? g.enc[0] : (part==1 ? g.enc[2] : (part==2 ? g.enc[4] : g.enc[6]));
          float eB = part==0 ? g.enc[1] : (part==1 ? g.enc[3] : (part==2 ? g.enc[5] : g.enc[7]));
          se_[et*9 + 2*part]     = pk2(eA, eA);
          se_[et*9 + 2*part + 1] = pk2(eB, eB);
        }
        if (part < 3) {
          float hv = part==0 ? h0 : (part==1 ? h1 : h2);
          sh_[et*3 + part] = hv;
        }
        wave_lds_fence();

        f4 accS = {0,0,0,0};
        #pragma unroll
        for (int s = 0; s < 12; s++) {
          const int m = 4*s + kg;
          const int l = m / 6;
          const int j = m - l*6;
          const uint4 ca = *(const uint4*)&sx_[row*28 + j*4];
          const h8 af = mul_enc(ca, se_[row*9 + l]);
          const h8 bf = as_h8(*(const uint4*)&smem[(s*64 + lane)*4]);
          accS = __builtin_amdgcn_mfma_f32_16x16x32_f16(af, bf, accS, 0, 0, 0);
        }
        f4 accA[3], accW[3];
        #pragma unroll
        for (int c = 0; c < 3; c++) { accA[c] = f4{0,0,0,0}; accW[c] = f4{0,0,0,0}; }
        #pragma unroll
        for (int c = 0; c < 3; c++) {
          #pragma unroll
          for (int s = 0; s < 6; s++) {
            const int m = 4*s + kg;
            const int l = m / 3;
            const int j = m - l*3;
            const uint4 ca = *(const uint4*)&sy_[row*44 + c*12 + j*4];
            const h8 af = mul_enc(ca, se_[row*9 + l]);
            const h8 bA = as_h8(*(const uint4*)&smem[3072 + (s*64 + lane)*4]);
            const h8 bW = as_h8(*(const uint4*)&smem[3072 + ((6 + s)*64 + lane)*4]);
            accA[c] = __builtin_amdgcn_mfma_f32_16x16x32_f16(af, bA, accA[c], 0, 0, 0);
            accW[c] = __builtin_amdgcn_mfma_f32_16x16x32_f16(af, bW, accW[c], 0, 0, 0);
          }
        }
        #pragma unroll
        for (int i = 0; i < 4; i++) {
          const int r = kg*4 + i;
          const float rh0 = sh_[r*3], rh1 = sh_[r*3+1], rh2 = sh_[r*3+2];
          const float sv = accS[i];
          const float A0 = accA[0][i], A1 = accA[1][i], A2 = accA[2][i];
          const float W0 = accW[0][i], W1 = accW[1][i], W2 = accW[2][i];
          nv0 += A0 + (rh1*W2 - rh2*W1) + rh0*sv;
          nv1 += A1 + (rh2*W0 - rh0*W2) + rh1*sv;
          nv2 += A2 + (rh0*W1 - rh1*W0) + rh2*sv;
        }
      }

      nv0 += __shfl_xor(nv0, 16, 64); nv0 += __shfl_xor(nv0, 32, 64);
      nv1 += __shfl_xor(nv1, 16, 64); nv1 += __shfl_xor(nv1, 32, 64);
      nv2 += __shfl_xor(nv2, 16, 64); nv2 += __shfl_xor(nv2, 32, 64);
      if (lane < 16) {
        float* o = outV + (size_t)n*48 + lane*3;
        o[0] = 0.1f*nv0; o[1] = 0.1f*nv1; o[2] = 0.1f*nv2;
      }
    }
  } else {
    u32* sa_ = smem + 4096 + wv*320;
    u32* sy_ = smem + 5376 + wv*704;
    u32* sxp = smem + 8192 + wv*704;
    u32* se_ = smem + 11008 + wv*144;
    float* sh_ = (float*)(smem + 11584) + wv*48;
    for (int n = bid*4 + wv; n < Nn; n += W) {
      const int beg = row_ptr[n], end = row_ptr[n+1];
      const int nch = (end - beg + 15) >> 4;
      float nd[9] = {0,0,0,0,0,0,0,0,0};

      for (int ch = 0; ch < nch; ch++) {
        const int ei = beg + ch*16 + et;
        const int e = (ei < end) ? sorted[ei] : -1;
        Geom g = {};
        const bool ok = (e >= 0) && geom_of(r_ij, e, g);
        float4 a0={0,0,0,0}, a1={0,0,0,0}, v0={0,0,0,0}, v1={0,0,0,0}, v2={0,0,0,0};
        float dd[18] = {0,0,0,0,0,0,0,0,0,0,0,0,0,0,0,0,0,0};
        if (ok) {
          const int nj = dst[e];
          const float4* xa4 = (const float4*)(x_a + (size_t)nj*32);
          a0 = xa4[2*part]; a1 = xa4[2*part+1];
          const float4* xv4 = (const float4*)(x_v + (size_t)nj*48);
          v0 = xv4[3*part]; v1 = xv4[3*part+1]; v2 = xv4[3*part+2];
          const float2* xd2 = (const float2*)(x_d + (size_t)nj*72) + 9*part;
          #pragma unroll
          for (int q = 0; q < 9; q++) { float2 f = xd2[q]; dd[2*q] = f.x; dd[2*q+1] = f.y; }
        }
        const float h0 = g.h0, h1 = g.h1, h2 = g.h2;
        sa_[et*20 + 4*part + 0] = pk2(a0.x, a0.y);
        sa_[et*20 + 4*part + 1] = pk2(a0.z, a0.w);
        sa_[et*20 + 4*part + 2] = pk2(a1.x, a1.y);
        sa_[et*20 + 4*part + 3] = pk2(a1.z, a1.w);
        sy_[et*44 + 0*12 + 2*part]     = pk2(v0.x, v0.w);
        sy_[et*44 + 0*12 + 2*part + 1] = pk2(v1.z, v2.y);
        sy_[et*44 + 1*12 + 2*part]     = pk2(v0.y, v1.x);
        sy_[et*44 + 1*12 + 2*part + 1] = pk2(v1.w, v2.z);
        sy_[et*44 + 2*12 + 2*part]     = pk2(v0.z, v1.y);
        sy_[et*44 + 2*12 + 2*part + 1] = pk2(v2.x, v2.w);
        #pragma unroll
        for (int c = 0; c < 3; c++) {
          float a = h0*dd[c]   + h1*dd[3+c]  + h2*dd[6+c];
          float b = h0*dd[9+c] + h1*dd[12+c] + h2*dd[15+c];
          sy_[et*44 + c*12 + 8 + part] = pk2(a, b);
        }
        #pragma unroll
        for (int ij = 0; ij < 9; ij++)
          sxp[et*44 + ij*4 + part] = pk2(dd[ij], dd[9+ij]);
        {
          float eA = part==0 ? g.enc[0] : (part==1 ? g.enc[2] : (part==2 ? g.enc[4] : g.enc[6]));
          float eB = part==0 ? g.enc[1] : (part==1 ? g.enc[3] : (part==2 ? g.enc[5] : g.enc[7]));
          se_[et*9 + 2*part]     = pk2(eA, eA);
          se_[et*9 + 2*part + 1] = pk2(eB, eB);
        }
        if (part < 3) {
          float hv = part==0 ? h0 : (part==1 ? h1 : h2);
          sh_[et*3 + part] = hv;
        }
        wave_lds_fence();

        f4 accSd = {0,0,0,0};
        #pragma unroll
        for (int s = 0; s < 8; s++) {
          const int m = 4*s + kg;
          const int l = m >> 2, j = m & 3;
          const uint4 ca = *(const uint4*)&sa_[row*20 + j*4];
          const h8 af = mul_enc(ca, se_[row*9 + l]);
          const h8 bf = as_h8(*(const uint4*)&smem[(s*64 + lane)*4]);
          accSd = __builtin_amdgcn_mfma_f32_16x16x32_f16(af, bf, accSd, 0, 0, 0);
        }
        f4 accY[3];
        #pragma unroll
        for (int c = 0; c < 3; c++) accY[c] = f4{0,0,0,0};
        #pragma unroll
        for (int c = 0; c < 3; c++) {
          #pragma unroll
          for (int s = 0; s < 6; s++) {
            const int m = 4*s + kg;
            const int l = m / 3;
            const int j = m - l*3;
            const uint4 ca = *(const uint4*)&sy_[row*44 + c*12 + j*4];
            const h8 af = mul_enc(ca, se_[row*9 + l]);
            const h8 bf = as_h8(*(const uint4*)&smem[2048 + (s*64 + lane)*4]);
            accY[c] = __builtin_amdgcn_mfma_f32_16x16x32_f16(af, bf, accY[c], 0, 0, 0);
          }
        }
        f4 accX[9];
        #pragma unroll
        for (int ij = 0; ij < 9; ij++) accX[ij] = f4{0,0,0,0};
        #pragma unroll
        for (int ij = 0; ij < 9; ij++) {
          const uint4 ca = *(const uint4*)&sxp[row*44 + ij*4];
          #pragma unroll
          for (int s = 0; s < 2; s++) {
            const h8 af = mul_enc(ca, se_[row*9 + 4*s + kg]);
            const h8 bf = as_h8(*(const uint4*)&smem[3584 + (s*64 + lane)*4]);
            accX[ij] = __builtin_amdgcn_mfma_f32_16x16x32_f16(af, bf, accX[ij], 0, 0, 0);
          }
        }
        #pragma unroll
        for (int i = 0; i < 4; i++) {
          const int r = kg*4 + i;
          const float rh0 = sh_[r*3], rh1 = sh_[r*3+1], rh2 = sh_[r*3+2];
          const float sd = accSd[i];
          const float A0 = accY[0][i], A1 = accY[1][i], A2 = accY[2][i];
          const float W0 = __shfl_xor(A0, 8, 64);
          const float W1 = __shfl_xor(A1, 8, 64);
          const float W2 = __shfl_xor(A2, 8, 64);
          const float q0 = A0 + (rh1*W2 - rh2*W1) + rh0*sd;
          const float q1 = A1 + (rh2*W0 - rh0*W2) + rh1*sd;
          const float q2 = A2 + (rh0*W1 - rh1*W0) + rh2*sd;
          nd[0] += accX[0][i] + rh0*q0;  nd[1] += accX[1][i] + rh0*q1;  nd[2] += accX[2][i] + rh0*q2;
          nd[3] += accX[3][i] + rh1*q0;  nd[4] += accX[4][i] + rh1*q1;  nd[5] += accX[5][i] + rh1*q2;
          nd[6] += accX[6][i] + rh2*q0;  nd[7] += accX[7][i] + rh2*q1;  nd[8] += accX[8][i] + rh2*q2;
        }
      }

      #pragma unroll
      for (int k = 0; k < 9; k++) {
        nd[k] += __shfl_xor(nd[k], 16, 64);
        nd[k] += __shfl_xor(nd[k], 32, 64);
      }
      if (lane < 8) {
        float* o = outD + (size_t)n*72 + lane*9;
        #pragma unroll
        for (int k = 0; k < 9; k++) o[k] = 0.1f*nd[k];
      }
    }
  }
}

// ======================= scalar fallback (insurance only) =======================
__global__ __launch_bounds__(256) void fallback_all(
    const float* __restrict__ r_ij, const float* __restrict__ x_a,
    const float* __restrict__ x_v,  const float* __restrict__ x_d,
    const float* __restrict__ P000, const float* __restrict__ P110, const float* __restrict__ P220,
    const float* __restrict__ P011, const float* __restrict__ P101, const float* __restrict__ P121,
    const float* __restrict__ P211, const float* __restrict__ P111,
    const float* __restrict__ P022, const float* __restrict__ P202, const float* __restrict__ P112,
    const float* __restrict__ P222, const float* __restrict__ P212,
    const int* __restrict__ src, const int* __restrict__ dst, int E,
    float* __restrict__ outA, float* __restrict__ outV, float* __restrict__ outD)
{
  const int e = blockIdx.x*256 + threadIdx.x;
  if (e >= E) return;
  Geom g;
  if (!geom_of(r_ij, e, g)) return;
  const int nj = dst[e], ni = src[e];
  const float* xa = x_a + (size_t)nj*32;
  const float* xv = x_v + (size_t)nj*48;
  const float* xd = x_d + (size_t)nj*72;
  float V0[16],V1[16],V2[16],s1[16],T0[8],T1[8],T2[8],s2[8];
  for (int b = 0; b < 16; b++) {
    V0[b]=xv[3*b]; V1[b]=xv[3*b+1]; V2[b]=xv[3*b+2];
    s1[b]=g.h0*V0[b]+g.h1*V1[b]+g.h2*V2[b];
  }
  for (int b = 0; b < 8; b++) {
    const float* m = xd + 9*b;
    T0[b]=g.h0*m[0]+g.h1*m[3]+g.h2*m[6];
    T1[b]=g.h0*m[1]+g.h1*m[4]+g.h2*m[7];
    T2[b]=g.h0*m[2]+g.h1*m[5]+g.h2*m[8];
    s2[b]=g.h0*T0[b]+g.h1*T1[b]+g.h2*T2[b];
  }
  for (int a = 0; a < 32; a++) {
    float acc = 0;
    for (int l = 0; l < 8; l++) {
      float u = 0;
      for (int b = 0; b < 32; b++) u += P000[(a*8+l)*32+b]*xa[b];
      for (int b = 0; b < 16; b++) u += P110[(a*8+l)*16+b]*s1[b];
      for (int b = 0; b < 8;  b++) u += P220[(a*8+l)*8+b]*s2[b];
      acc += g.enc[l]*u;
    }
    atomicAdd(outA + (size_t)ni*32 + a, 0.1f*acc);
  }
  for (int v = 0; v < 16; v++) {
    float sv=0,A0=0,A1=0,A2=0,W0=0,W1=0,W2=0;
    for (int l = 0; l < 8; l++) {
      const float el = g.enc[l];
      float u=0;
      for (int b=0;b<32;b++) u += P101[(v*8+l)*32+b]*xa[b];
      for (int b=0;b<16;b++) u += P211[(v*8+l)*16+b]*s1[b];
      sv += el*u;
      float a0=0,a1=0,a2=0,w0=0,w1=0,w2=0;
      for (int b=0;b<16;b++){float p=P011[(v*8+l)*16+b]; a0+=p*V0[b];a1+=p*V1[b];a2+=p*V2[b];}
      for (int b=0;b<8;b++){float p=P121[(v*8+l)*8+b]; a0+=p*T0[b];a1+=p*T1[b];a2+=p*T2[b];}
      for (int b=0;b<16;b++){float p=P111[(v*8+l)*16+b]; w0+=p*V0[b];w1+=p*V1[b];w2+=p*V2[b];}
      A0+=el*a0;A1+=el*a1;A2+=el*a2;W0+=el*w0;W1+=el*w1;W2+=el*w2;
    }
    float* o = outV + (size_t)ni*48 + v*3;
    atomicAdd(o+0, 0.1f*(A0 + (g.h1*W2-g.h2*W1) + g.h0*sv));
    atomicAdd(o+1, 0.1f*(A1 + (g.h2*W0-g.h0*W2) + g.h1*sv));
    atomicAdd(o+2, 0.1f*(A2 + (g.h0*W1-g.h1*W0) + g.h2*sv));
  }
  const float hh[3]={g.h0,g.h1,g.h2};
  for (int d = 0; d < 8; d++) {
    float sd=0,A0=0,A1=0,A2=0,W0=0,W1=0,W2=0;
    float w[8]={0,0,0,0,0,0,0,0};
    for (int l = 0; l < 8; l++) {
      const float el = g.enc[l];
      float u=0;
      for (int b=0;b<32;b++) u += P202[(d*8+l)*32+b]*xa[b];
      sd += el*u;
      float a0=0,a1=0,a2=0,w0=0,w1=0,w2=0;
      for (int b=0;b<16;b++){float p=P112[(d*8+l)*16+b]; a0+=p*V0[b];a1+=p*V1[b];a2+=p*V2[b];}
      for (int b=0;b<8;b++){float p=P222[(d*8+l)*8+b]; a0+=p*T0[b];a1+=p*T1[b];a2+=p*T2[b];}
      for (int b=0;b<16;b++){float p=P212[(d*8+l)*16+b]; w0+=p*V0[b];w1+=p*V1[b];w2+=p*V2[b];}
      A0+=el*a0;A1+=el*a1;A2+=el*a2;W0+=el*w0;W1+=el*w1;W2+=el*w2;
      for (int b=0;b<8;b++) w[b]+=el*P022[(d*8+l)*8+b];
    }
    const float q[3] = { A0+(g.h1*W2-g.h2*W1)+g.h0*sd,
                         A1+(g.h2*W0-g.h0*W2)+g.h1*sd,
                         A2+(g.h0*W1-g.h1*W0)+g.h2*sd };
    float* o = outD + (size_t)ni*72 + d*9;
    for (int ii = 0; ii < 3; ii++)
      for (int jj = 0; jj < 3; jj++) {
        float acc = 0;
        for (int b = 0; b < 8; b++) acc += w[b]*xd[9*b + ii*3 + jj];
        atomicAdd(o + ii*3 + jj, 0.1f*(acc + hh[ii]*q[jj]));
      }
  }
}

extern "C" void kernel_launch(void* const* d_in, const int* in_sizes, int n_in,
                              void* d_out, int out_size, void* d_ws, size_t ws_size,
                              hipStream_t stream) {
  const float* r_ij = (const float*)d_in[0];
  const float* x_a  = (const float*)d_in[1];
  const float* x_v  = (const float*)d_in[2];
  const float* x_d  = (const float*)d_in[3];
  const float* P000 = (const float*)d_in[4];
  const float* P110 = (const float*)d_in[5];
  const float* P220 = (const float*)d_in[6];
  const float* P011 = (const float*)d_in[7];
  const float* P101 = (const float*)d_in[8];
  const float* P121 = (const float*)d_in[9];
  const float* P211 = (const float*)d_in[10];
  const float* P111 = (const float*)d_in[11];
  const float* P022 = (const float*)d_in[12];
  const float* P202 = (const float*)d_in[13];
  const float* P112 = (const float*)d_in[14];
  const float* P222 = (const float*)d_in[15];
  const float* P212 = (const float*)d_in[16];
  const int* src = (const int*)d_in[17];
  const int* dst = (const int*)d_in[18];

  const int E  = in_sizes[17];
  const int Nn = in_sizes[1] / 32;
  float* out  = (float*)d_out;
  float* outA = out;
  float* outV = out + (size_t)Nn*32;
  float* outD = out + (size_t)Nn*80;

  const size_t need = 4ull * (2ull*(size_t)Nn + 1 + (size_t)E);
  if (ws_size >= need) {
    int* hist    = (int*)d_ws;
    int* row_ptr = hist + Nn;
    int* sorted  = row_ptr + Nn + 1;
    hipMemsetAsync(hist, 0, (size_t)Nn*sizeof(int), stream);
    hist_k   <<<(E + 255)/256, 256, 0, stream>>>(r_ij, src, E, hist);
    scan_k   <<<1, 1024, 0, stream>>>(hist, Nn, row_ptr);
    scatter_k<<<(E + 255)/256, 256, 0, stream>>>(r_ij, src, E, hist, sorted);

    const int gS = 192, gV = 288, gD = 288;   // 768 blocks = 3/CU (47KB LDS)
    msgAll_k<<<gS + gV + gD, 256, 0, stream>>>(r_ij, x_a, x_v, x_d,
        P000, P110, P220, P011, P101, P121, P211, P111,
        P022, P202, P112, P222, P212,
        dst, row_ptr, sorted, Nn, gS, gV, outA, outV, outD);
  } else {
    hipMemsetAsync(d_out, 0, (size_t)out_size * sizeof(float), stream);
    fallback_all<<<(E + 255)/256, 256, 0, stream>>>(r_ij, x_a, x_v, x_d,
        P000, P110, P220, P011, P101, P121, P211, P111,
        P022, P202, P112, P222, P212, src, dst, E, outA, outV, outD);
  }
}